// Round 2
// baseline (209.239 us; speedup 1.0000x reference)
//
#include <hip/hip_runtime.h>

// Problem constants (B=8, C=256, H=W=128, L=512)
#define BATCH 8
#define CIN   256
#define LDIM  512
#define HDIM  128
#define WDIM  128
#define HWN   (HDIM * WDIM)      // 16384
#define PH    64                  // prev_rgb spatial
#define PW    64

// ---------------------------------------------------------------------------
// Kernel 1: style = istyle @ style_w.T + style_b ; wmod[b,o,c] = conv_w[o,c]*(style+1)
// grid = BATCH*CIN blocks of 64 threads (1 wave each). Coalesced over L.
// ---------------------------------------------------------------------------
__global__ __launch_bounds__(64)
void style_weights_kernel(const float* __restrict__ istyle,   // [B, L]
                          const float* __restrict__ style_w,  // [C, L]
                          const float* __restrict__ style_b,  // [C]
                          const float* __restrict__ conv_w,   // [3, C]
                          float* __restrict__ wmod) {         // [B, 3, C]
    const int bid = blockIdx.x;          // 0 .. B*C-1
    const int b = bid >> 8;              // bid / CIN
    const int c = bid & (CIN - 1);
    const int t = threadIdx.x;           // 0..63

    const float* is = istyle + b * LDIM;
    const float* sw = style_w + c * LDIM;

    float p = 0.0f;
#pragma unroll
    for (int l = t; l < LDIM; l += 64) p += is[l] * sw[l];

    // wave64 butterfly reduce
#pragma unroll
    for (int off = 32; off > 0; off >>= 1) p += __shfl_down(p, off);

    if (t == 0) {
        const float s = p + style_b[c] + 1.0f;
        wmod[(b * 3 + 0) * CIN + c] = conv_w[0 * CIN + c] * s;
        wmod[(b * 3 + 1) * CIN + c] = conv_w[1 * CIN + c] * s;
        wmod[(b * 3 + 2) * CIN + c] = conv_w[2 * CIN + c] * s;
    }
}

// ---------------------------------------------------------------------------
// Kernel 2: out[b,o,pos] = sum_c wmod[b,o,c]*x[b,c,pos] + rgb_bias[o] + upsample
// One thread per output spatial position; 512 blocks x 256 threads.
// ---------------------------------------------------------------------------
__global__ __launch_bounds__(256)
void rgb_main_kernel(const float* __restrict__ x,        // [B, C, H, W]
                     const float* __restrict__ prev,     // [B, 3, 64, 64]
                     const float* __restrict__ rgb_bias, // [3]
                     const float* __restrict__ wmod,     // [B, 3, C]
                     float* __restrict__ out) {          // [B, 3, H, W]
    __shared__ float sw[3 * CIN];

    const int idx = blockIdx.x * 256 + threadIdx.x;   // 0 .. B*HW-1
    const int b   = idx >> 14;                        // idx / HWN
    const int pos = idx & (HWN - 1);

    // stage this batch's 768 modulated weights into LDS
    for (int i = threadIdx.x; i < 3 * CIN; i += 256)
        sw[i] = wmod[b * 3 * CIN + i];
    __syncthreads();

    const float* xp = x + ((size_t)b * CIN) * HWN + pos;

    float a0 = 0.0f, a1 = 0.0f, a2 = 0.0f;
#pragma unroll 16
    for (int c = 0; c < CIN; ++c) {
        const float v = xp[(size_t)c * HWN];   // coalesced across the wave
        a0 += v * sw[c];                        // LDS same-address broadcast
        a1 += v * sw[CIN + c];
        a2 += v * sw[2 * CIN + c];
    }

    // --- bilinear x2 upsample, half-pixel centers, edge clamp ---
    const int h = pos >> 7;
    const int w = pos & (WDIM - 1);
    const float shf = h * 0.5f - 0.25f;
    const float swf = w * 0.5f - 0.25f;
    const float fh = shf - floorf(shf);   // 0.25 or 0.75
    const float fw = swf - floorf(swf);
    int h0 = (int)floorf(shf), w0 = (int)floorf(swf);
    int h1 = min(h0 + 1, PH - 1), w1 = min(w0 + 1, PW - 1);
    h0 = max(h0, 0);
    w0 = max(w0, 0);

    const float* pb = prev + (size_t)b * 3 * PH * PW;
    float up[3];
#pragma unroll
    for (int o = 0; o < 3; ++o) {
        const float* p = pb + o * PH * PW;
        const float v00 = p[h0 * PW + w0];
        const float v01 = p[h0 * PW + w1];
        const float v10 = p[h1 * PW + w0];
        const float v11 = p[h1 * PW + w1];
        const float top = v00 + (v01 - v00) * fw;
        const float bot = v10 + (v11 - v10) * fw;
        up[o] = top + (bot - top) * fh;
    }

    out[((size_t)b * 3 + 0) * HWN + pos] = a0 + rgb_bias[0] + up[0];
    out[((size_t)b * 3 + 1) * HWN + pos] = a1 + rgb_bias[1] + up[1];
    out[((size_t)b * 3 + 2) * HWN + pos] = a2 + rgb_bias[2] + up[2];
}

// ---------------------------------------------------------------------------
extern "C" void kernel_launch(void* const* d_in, const int* in_sizes, int n_in,
                              void* d_out, int out_size, void* d_ws, size_t ws_size,
                              hipStream_t stream) {
    const float* x        = (const float*)d_in[0];  // [8,256,128,128]
    const float* prev_rgb = (const float*)d_in[1];  // [8,3,64,64]
    const float* istyle   = (const float*)d_in[2];  // [8,512]
    const float* style_w  = (const float*)d_in[3];  // [256,512]
    const float* style_b  = (const float*)d_in[4];  // [256]
    const float* conv_w   = (const float*)d_in[5];  // [3,256]
    const float* rgb_bias = (const float*)d_in[6];  // [3]
    float* out = (float*)d_out;
    float* wmod = (float*)d_ws;                     // [8,3,256] = 24 KB

    style_weights_kernel<<<BATCH * CIN, 64, 0, stream>>>(
        istyle, style_w, style_b, conv_w, wmod);

    rgb_main_kernel<<<(BATCH * HWN) / 256, 256, 0, stream>>>(
        x, prev_rgb, rgb_bias, wmod, out);
}